// Round 2
// baseline (186.496 us; speedup 1.0000x reference)
//
#include <hip/hip_runtime.h>
#include <hip/hip_bf16.h>

typedef unsigned short u16;
typedef __attribute__((ext_vector_type(8))) short bf16x8;
typedef __attribute__((ext_vector_type(4))) float f32x4;

#define B_ 16
#define CIN 256
#define COUT 256
#define NPIX 4096
#define E_ 8
#define HP 66            // halo-padded width/height
#define PPIX (HP*HP)     // 4356 padded pixels per sample

__device__ __forceinline__ u16 f2bf(float f){
    union { float f; unsigned int u; } v; v.f = f;
    return (u16)((v.u + 0x7FFFu + ((v.u >> 16) & 1u)) >> 16);
}

__device__ __forceinline__ void gload(const u16* g, u16* l){
    __builtin_amdgcn_global_load_lds(
        (const __attribute__((address_space(1))) unsigned int*)g,
        (__attribute__((address_space(3))) unsigned int*)l, 16, 0, 0);
}

// -------- 0) zero halo borders of xt2 + zero pooled --------
__global__ void k_zero(u16* __restrict__ xt2, float* __restrict__ pooled){
    int gid = blockIdx.x*256 + threadIdx.x;
    if (gid < B_*CIN) pooled[gid] = 0.f;
    int u4 = gid & 31;           // which 16B chunk of the 512B pixel row
    int pl = gid >> 5;
    if (pl >= B_*260) return;    // 260 border pixels per sample
    int b = pl / 260;
    int pi = pl - b*260;
    int y, x;
    if (pi < 66)      { y = 0;  x = pi; }
    else if (pi < 132){ y = 65; x = pi - 66; }
    else { int q = pi - 132; y = 1 + (q >> 1); x = (q & 1) ? 65 : 0; }
    uint4 z = {0u,0u,0u,0u};
    *(uint4*)(xt2 + ((size_t)b*PPIX + y*HP + x)*CIN + u4*8) = z;
}

// -------- 1) transpose+convert x -> xt2[b][(y+1)*66+(x+1)][cin] bf16, fused avg-pool sum --------
__global__ void k_xt(const float* __restrict__ x, u16* __restrict__ xt2,
                     float* __restrict__ pooled){
    __shared__ float tile[64][65];
    int bid = blockIdx.x;
    int b = bid >> 8, ct = (bid >> 6) & 3, pt = bid & 63;
    int c0 = ct*64, p0 = pt*64, t = threadIdx.x;
    #pragma unroll
    for (int iter = 0; iter < 4; ++iter){
        int idx = t*4 + iter*1024;
        int r = idx >> 6, c4 = idx & 63;
        float4 v = *(const float4*)(x + ((size_t)(b*CIN + c0 + r))*NPIX + p0 + c4);
        tile[r][c4+0] = v.x; tile[r][c4+1] = v.y; tile[r][c4+2] = v.z; tile[r][c4+3] = v.w;
        // fused pooling: 16 consecutive lanes hold one channel-row of 64 px
        float rs = v.x + v.y + v.z + v.w;
        #pragma unroll
        for (int off = 1; off < 16; off <<= 1) rs += __shfl_xor(rs, off, 64);
        if ((t & 15) == 0) atomicAdd(&pooled[b*CIN + c0 + r], rs);
    }
    __syncthreads();
    #pragma unroll
    for (int iter = 0; iter < 4; ++iter){
        int idx = t*4 + iter*1024;
        int pr = idx >> 6, cc = idx & 63;
        ushort4 u;
        u.x = f2bf(tile[cc+0][pr]);
        u.y = f2bf(tile[cc+1][pr]);
        u.z = f2bf(tile[cc+2][pr]);
        u.w = f2bf(tile[cc+3][pr]);
        int p = p0 + pr;
        int yy = p >> 6, xx = p & 63;
        *(ushort4*)(xt2 + ((size_t)b*PPIX + (yy+1)*HP + (xx+1))*CIN + c0 + cc) = u;
    }
}

// -------- 2) routing + aggregated bias (pooled holds SUM, scale by 1/4096) --------
__global__ void k_route(const float* __restrict__ pooled, const float* __restrict__ rw,
                        const float* __restrict__ rb, const float* __restrict__ bias,
                        float* __restrict__ routing, float* __restrict__ aggb)
{
    __shared__ float r_s[B_*E_];
    int t = threadIdx.x;
    if (t < B_*E_){
        int b = t >> 3, e = t & 7;
        float s = 0.f;
        const float* pp = pooled + b*CIN;
        const float* wp = rw + e*CIN;
        for (int i = 0; i < CIN; ++i) s += pp[i]*wp[i];
        s = s * (1.0f/(float)NPIX) + rb[e];
        float r = 1.0f/(1.0f + __expf(-s));
        routing[t] = r;
        r_s[t] = r;
    }
    __syncthreads();
    for (int idx = t; idx < B_*COUT; idx += 256){
        int b = idx >> 8, o = idx & 255;
        float s = 0.f;
        #pragma unroll
        for (int e = 0; e < E_; ++e) s += r_s[b*E_+e]*bias[e*COUT+o];
        aggb[idx] = s;
    }
}

// -------- 3) aggregated weights, bf16, layout [b][o][tap][cin] --------
__global__ void k_aggw(const float* __restrict__ weight, const float* __restrict__ routing,
                       u16* __restrict__ aggw)
{
    int o = blockIdx.x, i = threadIdx.x;
    __shared__ float r_s[B_*E_];
    if (i < B_*E_) r_s[i] = routing[i];
    __syncthreads();
    float w[E_][9];
    #pragma unroll
    for (int e = 0; e < E_; ++e){
        const float* wp = weight + (((size_t)(e*COUT + o))*CIN + i)*9;
        #pragma unroll
        for (int tp = 0; tp < 9; ++tp) w[e][tp] = wp[tp];
    }
    for (int b = 0; b < B_; ++b){
        float acc[9];
        #pragma unroll
        for (int tp = 0; tp < 9; ++tp) acc[tp] = 0.f;
        #pragma unroll
        for (int e = 0; e < E_; ++e){
            float r = r_s[b*E_+e];
            #pragma unroll
            for (int tp = 0; tp < 9; ++tp) acc[tp] += r*w[e][tp];
        }
        #pragma unroll
        for (int tp = 0; tp < 9; ++tp)
            aggw[(((size_t)(b*COUT + o))*9 + tp)*CIN + i] = f2bf(acc[tp]);
    }
}

// -------- 4) implicit-GEMM conv, m97 structure: global_load_lds + linear LDS --------
__global__ __launch_bounds__(256) void k_conv(
    const u16* __restrict__ aggw, const u16* __restrict__ xt2,
    const float* __restrict__ aggb, float* __restrict__ out)
{
    __shared__ __align__(16) u16 As[128*32];   // [m][kk] linear, 8 KB
    __shared__ __align__(16) u16 Bs[128*32];   // [p][kk] linear, 8 KB

    // XCD-chunked swizzle (1024 blocks, 8 XCDs -> 128 contiguous per XCD)
    int orig = blockIdx.x;
    int bid = (orig & 7)*128 + (orig >> 3);

    int b  = bid >> 6;
    int mt = (bid >> 5) & 1;
    int pt = bid & 31;
    int m0 = mt << 7;
    int p0 = pt << 7;

    int t = threadIdx.x;
    int lane = t & 63;
    int w = t >> 6;
    int wm = (w >> 1) << 6;
    int wn = (w & 1) << 6;
    int l16 = lane & 15;
    int g8 = (lane >> 4) << 3;

    int arow = t >> 2;           // staging row / pixel-x within chunk (0..63)
    int kk   = (t & 3) << 3;     // staging k chunk (u16 units)
    int y0   = pt << 1;          // output rows y0, y0+1

    const u16* baseA0 = aggw + ((size_t)(b*COUT + m0 + arow))*(9*CIN) + kk;
    const u16* baseA1 = baseA0 + (size_t)64*(9*CIN);
    const u16* baseB  = xt2 + ((size_t)b*PPIX + y0*HP + arow)*CIN + kk;

    u16* ldsA0 = As + w*512;
    u16* ldsA1 = As + 2048 + w*512;
    u16* ldsB0 = Bs + w*512;
    u16* ldsB1 = Bs + 2048 + w*512;

    f32x4 acc[4][4];
    #pragma unroll
    for (int i = 0; i < 4; ++i)
        #pragma unroll
        for (int j = 0; j < 4; ++j){
            f32x4 z = {0.f,0.f,0.f,0.f};
            acc[i][j] = z;
        }

    for (int tap = 0; tap < 9; ++tap){
        int kh = tap / 3, kw = tap - kh*3;
        int aoff = tap << 8;                    // tap*CIN
        int bo0  = (kh*HP + kw) << 8;           // chunk j=0 (y=y0)
        int bo1  = ((kh+1)*HP + kw) << 8;       // chunk j=1 (y=y0+1)
        #pragma unroll
        for (int c0 = 0; c0 < CIN; c0 += 32){
            gload(baseA0 + aoff + c0, ldsA0);
            gload(baseA1 + aoff + c0, ldsA1);
            gload(baseB + bo0 + c0, ldsB0);
            gload(baseB + bo1 + c0, ldsB1);
            __syncthreads();                    // vmcnt drain -> tiles ready

            bf16x8 af[4], bv[4];
            #pragma unroll
            for (int mf = 0; mf < 4; ++mf)
                af[mf] = *(const bf16x8*)(As + (wm + mf*16 + l16)*32 + g8);
            #pragma unroll
            for (int nf = 0; nf < 4; ++nf)
                bv[nf] = *(const bf16x8*)(Bs + (wn + nf*16 + l16)*32 + g8);
            #pragma unroll
            for (int mf = 0; mf < 4; ++mf)
                #pragma unroll
                for (int nf = 0; nf < 4; ++nf)
                    acc[mf][nf] = __builtin_amdgcn_mfma_f32_16x16x32_bf16(
                        af[mf], bv[nf], acc[mf][nf], 0, 0, 0);

            __syncthreads();                    // reads done before next stage
        }
    }

    const float* ab = aggb + b*COUT + m0;
    float* outp = out + ((size_t)(b*COUT + m0))*NPIX + p0;
    #pragma unroll
    for (int mf = 0; mf < 4; ++mf){
        #pragma unroll
        for (int v = 0; v < 4; ++v){
            int r = wm + mf*16 + (g8 >> 1) + v;
            float bias_r = ab[r];
            float* orow = outp + (size_t)r*NPIX;
            #pragma unroll
            for (int nf = 0; nf < 4; ++nf)
                orow[wn + nf*16 + l16] = acc[mf][nf][v] + bias_r;
        }
    }
}

extern "C" void kernel_launch(void* const* d_in, const int* in_sizes, int n_in,
                              void* d_out, int out_size, void* d_ws, size_t ws_size,
                              hipStream_t stream)
{
    const float* x      = (const float*)d_in[0];
    const float* weight = (const float*)d_in[1];
    const float* bias   = (const float*)d_in[2];
    const float* rw     = (const float*)d_in[3];
    const float* rb     = (const float*)d_in[4];
    float* out = (float*)d_out;

    char* ws = (char*)d_ws;
    u16*   aggw    = (u16*)(ws);                          // 18,874,368 B
    u16*   xt2     = (u16*)(ws + 18874368);               // 35,684,352 B (halo 66x66)
    float* pooled  = (float*)(ws + 54558720);             // 16 KB
    float* routing = (float*)(ws + 54558720 + 16384);     // 512 B
    float* aggb    = (float*)(ws + 54558720 + 16384 + 512); // 16 KB

    k_zero <<<520,  256, 0, stream>>>(xt2, pooled);
    k_xt   <<<4096, 256, 0, stream>>>(x, xt2, pooled);
    k_route<<<1,    256, 0, stream>>>(pooled, rw, rb, bias, routing, aggb);
    k_aggw <<<COUT, 256, 0, stream>>>(weight, routing, aggw);
    k_conv <<<1024, 256, 0, stream>>>(aggw, xt2, aggb, out);
}

// Round 3
// 143.420 us; speedup vs baseline: 1.3004x; 1.3004x over previous
//
#include <hip/hip_runtime.h>
#include <hip/hip_bf16.h>

typedef unsigned short u16;
typedef __attribute__((ext_vector_type(8))) short bf16x8;
typedef __attribute__((ext_vector_type(4))) float f32x4;

#define B_ 16
#define CIN 256
#define COUT 256
#define NPIX 4096
#define E_ 8
#define HP 66            // halo-padded width/height
#define PPIX (HP*HP)     // 4356 padded pixels per sample
#define KTOT 2304        // 9 * 256
#define NKT 36           // K-tiles of 64

__device__ __forceinline__ u16 f2bf(float f){
    union { float f; unsigned int u; } v; v.f = f;
    return (u16)((v.u + 0x7FFFu + ((v.u >> 16) & 1u)) >> 16);
}

__device__ __forceinline__ void gload(const u16* g, u16* l){
    __builtin_amdgcn_global_load_lds(
        (const __attribute__((address_space(1))) unsigned int*)g,
        (__attribute__((address_space(3))) unsigned int*)l, 16, 0, 0);
}

// -------- 0) zero halo borders of xt2 + zero pooled --------
__global__ void k_zero(u16* __restrict__ xt2, float* __restrict__ pooled){
    int gid = blockIdx.x*256 + threadIdx.x;
    if (gid < B_*CIN) pooled[gid] = 0.f;
    int u4 = gid & 31;
    int pl = gid >> 5;
    if (pl >= B_*260) return;
    int b = pl / 260;
    int pi = pl - b*260;
    int y, x;
    if (pi < 66)      { y = 0;  x = pi; }
    else if (pi < 132){ y = 65; x = pi - 66; }
    else { int q = pi - 132; y = 1 + (q >> 1); x = (q & 1) ? 65 : 0; }
    uint4 z = {0u,0u,0u,0u};
    *(uint4*)(xt2 + ((size_t)b*PPIX + y*HP + x)*CIN + u4*8) = z;
}

// -------- 1) transpose+convert x -> xt2[b][(y+1)*66+(x+1)][cin] bf16, fused pool --------
__global__ void k_xt(const float* __restrict__ x, u16* __restrict__ xt2,
                     float* __restrict__ pooled){
    __shared__ float tile[64][65];
    int bid = blockIdx.x;
    int b = bid >> 8, ct = (bid >> 6) & 3, pt = bid & 63;
    int c0 = ct*64, p0 = pt*64, t = threadIdx.x;
    #pragma unroll
    for (int iter = 0; iter < 4; ++iter){
        int idx = t*4 + iter*1024;
        int r = idx >> 6, c4 = idx & 63;
        float4 v = *(const float4*)(x + ((size_t)(b*CIN + c0 + r))*NPIX + p0 + c4);
        tile[r][c4+0] = v.x; tile[r][c4+1] = v.y; tile[r][c4+2] = v.z; tile[r][c4+3] = v.w;
        float rs = v.x + v.y + v.z + v.w;
        #pragma unroll
        for (int off = 1; off < 16; off <<= 1) rs += __shfl_xor(rs, off, 64);
        if ((t & 15) == 0) atomicAdd(&pooled[b*CIN + c0 + r], rs);
    }
    __syncthreads();
    #pragma unroll
    for (int iter = 0; iter < 4; ++iter){
        int idx = t*4 + iter*1024;
        int pr = idx >> 6, cc = idx & 63;
        ushort4 u;
        u.x = f2bf(tile[cc+0][pr]);
        u.y = f2bf(tile[cc+1][pr]);
        u.z = f2bf(tile[cc+2][pr]);
        u.w = f2bf(tile[cc+3][pr]);
        int p = p0 + pr;
        int yy = p >> 6, xx = p & 63;
        *(ushort4*)(xt2 + ((size_t)b*PPIX + (yy+1)*HP + (xx+1))*CIN + c0 + cc) = u;
    }
}

// -------- 2) routing + aggregated bias --------
__global__ void k_route(const float* __restrict__ pooled, const float* __restrict__ rw,
                        const float* __restrict__ rb, const float* __restrict__ bias,
                        float* __restrict__ routing, float* __restrict__ aggb)
{
    __shared__ float r_s[B_*E_];
    int t = threadIdx.x;
    if (t < B_*E_){
        int b = t >> 3, e = t & 7;
        float s = 0.f;
        const float* pp = pooled + b*CIN;
        const float* wp = rw + e*CIN;
        for (int i = 0; i < CIN; ++i) s += pp[i]*wp[i];
        s = s * (1.0f/(float)NPIX) + rb[e];
        float r = 1.0f/(1.0f + __expf(-s));
        routing[t] = r;
        r_s[t] = r;
    }
    __syncthreads();
    for (int idx = t; idx < B_*COUT; idx += 256){
        int b = idx >> 8, o = idx & 255;
        float s = 0.f;
        #pragma unroll
        for (int e = 0; e < E_; ++e) s += r_s[b*E_+e]*bias[e*COUT+o];
        aggb[idx] = s;
    }
}

// -------- 3) aggregated weights, bf16, layout [b][o][tap][cin] --------
__global__ void k_aggw(const float* __restrict__ weight, const float* __restrict__ routing,
                       u16* __restrict__ aggw)
{
    int o = blockIdx.x, i = threadIdx.x;
    __shared__ float r_s[B_*E_];
    if (i < B_*E_) r_s[i] = routing[i];
    __syncthreads();
    float w[E_][9];
    #pragma unroll
    for (int e = 0; e < E_; ++e){
        const float* wp = weight + (((size_t)(e*COUT + o))*CIN + i)*9;
        #pragma unroll
        for (int tp = 0; tp < 9; ++tp) w[e][tp] = wp[tp];
    }
    for (int b = 0; b < B_; ++b){
        float acc[9];
        #pragma unroll
        for (int tp = 0; tp < 9; ++tp) acc[tp] = 0.f;
        #pragma unroll
        for (int e = 0; e < E_; ++e){
            float r = r_s[b*E_+e];
            #pragma unroll
            for (int tp = 0; tp < 9; ++tp) acc[tp] += r*w[e][tp];
        }
        #pragma unroll
        for (int tp = 0; tp < 9; ++tp)
            aggw[(((size_t)(b*COUT + o))*9 + tp)*CIN + i] = f2bf(acc[tp]);
    }
}

// -------- 4) 256x256-tile implicit-GEMM conv, prefetch-1-tile dbuf, swizzled LDS --------
__global__ __launch_bounds__(512, 2) void k_conv(
    const u16* __restrict__ aggw, const u16* __restrict__ xt2,
    const float* __restrict__ aggb, float* __restrict__ out)
{
    // 128 KB LDS: 2 buffers x (A 256x64 + B 256x64) bf16
    __shared__ __align__(16) u16 lds[65536];

    // bijective XCD swizzle: 256 blocks -> 32 consecutive per XCD (2 samples/XCD)
    int orig = blockIdx.x;
    int bid = (orig & 7)*32 + (orig >> 3);

    int b  = bid >> 4;          // sample
    int nt = bid & 15;          // pixel tile (256 px = 4 image rows)
    int y0 = nt << 2;

    int t = threadIdx.x;
    int lane = t & 63;
    int w = t >> 6;
    int wm = (w >> 2) << 7;     // 0 / 128
    int wn = (w & 3) << 6;      // 0 / 64 / 128 / 192
    int l16 = lane & 15;
    int kh4 = lane >> 4;        // 0..3 (k-chunk within 32-k block is kh4*8)
    int sw  = l16 & 7;          // read-side swizzle key (row & 7)

    // staging coords: thread t covers LDS row (t>>3)+i*64, chunk t&7
    int tr = t >> 3;            // 0..63
    int tc = t & 7;
    int sc = tc ^ (tr & 7);     // pre-swizzled source chunk

    const u16* aSrc = aggw + (size_t)b*COUT*9*CIN + (size_t)tr*KTOT + sc*8;
    const u16* bSrc = xt2 + ((size_t)b*PPIX + (size_t)y0*HP + tr)*CIN + sc*8;

    f32x4 acc[8][4];
    #pragma unroll
    for (int i = 0; i < 8; ++i)
        #pragma unroll
        for (int j = 0; j < 4; ++j){
            f32x4 z = {0.f,0.f,0.f,0.f};
            acc[i][j] = z;
        }

    auto stage = [&](int kt, int bufn){
        int tap = kt >> 2;
        int c0  = (kt & 3) << 6;
        int kh  = tap / 3, kw = tap - kh*3;
        const u16* a0 = aSrc + tap*CIN + c0;
        const u16* b0 = bSrc + (kh*HP + kw)*CIN + c0;
        u16* dA = lds + bufn*32768 + w*512;
        u16* dB = dA + 16384;
        #pragma unroll
        for (int i = 0; i < 4; ++i)
            gload(a0 + (size_t)i*64*KTOT, dA + i*4096);
        #pragma unroll
        for (int i = 0; i < 4; ++i)
            gload(b0 + (size_t)i*HP*CIN, dB + i*4096);
    };

    // swizzled chunk byte offsets for the two 32-k halves (u16 units)
    int ck0 = ((kh4    ) ^ sw) * 8;
    int ck1 = ((kh4 | 4) ^ sw) * 8;

    stage(0, 0);
    __syncthreads();

    int buf = 0;
    for (int kt = 0; kt < NKT; ++kt){
        if (kt < NKT-1) stage(kt+1, buf^1);

        const u16* LA = lds + buf*32768;
        const u16* LB = LA + 16384;

        #pragma unroll
        for (int qm = 0; qm < 2; ++qm){
            bf16x8 af[4][2];
            #pragma unroll
            for (int mf = 0; mf < 4; ++mf){
                int ro = (wm + qm*64 + mf*16 + l16) * 64;
                af[mf][0] = *(const bf16x8*)(LA + ro + ck0);
                af[mf][1] = *(const bf16x8*)(LA + ro + ck1);
            }
            #pragma unroll
            for (int qn = 0; qn < 2; ++qn){
                bf16x8 bfr[2][2];
                #pragma unroll
                for (int nf = 0; nf < 2; ++nf){
                    int ro = (wn + qn*32 + nf*16 + l16) * 64;
                    bfr[nf][0] = *(const bf16x8*)(LB + ro + ck0);
                    bfr[nf][1] = *(const bf16x8*)(LB + ro + ck1);
                }
                __builtin_amdgcn_s_setprio(1);
                #pragma unroll
                for (int mf = 0; mf < 4; ++mf)
                    #pragma unroll
                    for (int nf = 0; nf < 2; ++nf){
                        acc[qm*4+mf][qn*2+nf] = __builtin_amdgcn_mfma_f32_16x16x32_bf16(
                            af[mf][0], bfr[nf][0], acc[qm*4+mf][qn*2+nf], 0, 0, 0);
                        acc[qm*4+mf][qn*2+nf] = __builtin_amdgcn_mfma_f32_16x16x32_bf16(
                            af[mf][1], bfr[nf][1], acc[qm*4+mf][qn*2+nf], 0, 0, 0);
                    }
                __builtin_amdgcn_s_setprio(0);
            }
        }
        __syncthreads();   // drains vmcnt(0): next buffer fully staged
        buf ^= 1;
    }

    // epilogue: += aggregated bias, write fp32
    const float* ab = aggb + b*COUT;
    float* outp = out + ((size_t)b*COUT)*NPIX + nt*256;
    #pragma unroll
    for (int mf8 = 0; mf8 < 8; ++mf8){
        #pragma unroll
        for (int v = 0; v < 4; ++v){
            int r = wm + mf8*16 + kh4*4 + v;
            float bias_r = ab[r];
            float* orow = outp + (size_t)r*NPIX;
            #pragma unroll
            for (int nf = 0; nf < 4; ++nf)
                orow[wn + nf*16 + l16] = acc[mf8][nf][v] + bias_r;
        }
    }
}

extern "C" void kernel_launch(void* const* d_in, const int* in_sizes, int n_in,
                              void* d_out, int out_size, void* d_ws, size_t ws_size,
                              hipStream_t stream)
{
    const float* x      = (const float*)d_in[0];
    const float* weight = (const float*)d_in[1];
    const float* bias   = (const float*)d_in[2];
    const float* rw     = (const float*)d_in[3];
    const float* rb     = (const float*)d_in[4];
    float* out = (float*)d_out;

    char* ws = (char*)d_ws;
    u16*   aggw    = (u16*)(ws);                          // 18,874,368 B
    u16*   xt2     = (u16*)(ws + 18874368);               // 35,684,352 B (halo 66x66)
    float* pooled  = (float*)(ws + 54558720);             // 16 KB
    float* routing = (float*)(ws + 54558720 + 16384);     // 512 B
    float* aggb    = (float*)(ws + 54558720 + 16384 + 512); // 16 KB

    k_zero <<<520,  256, 0, stream>>>(xt2, pooled);
    k_xt   <<<4096, 256, 0, stream>>>(x, xt2, pooled);
    k_route<<<1,    256, 0, stream>>>(pooled, rw, rb, bias, routing, aggb);
    k_aggw <<<COUT, 256, 0, stream>>>(weight, routing, aggw);
    k_conv <<<256,  512, 0, stream>>>(aggw, xt2, aggb, out);
}

// Round 4
// 142.458 us; speedup vs baseline: 1.3091x; 1.0067x over previous
//
#include <hip/hip_runtime.h>
#include <hip/hip_bf16.h>

typedef unsigned short u16;
typedef __attribute__((ext_vector_type(8))) short bf16x8;
typedef __attribute__((ext_vector_type(4))) float f32x4;

#define B_ 16
#define CIN 256
#define COUT 256
#define NPIX 4096
#define E_ 8
#define HP 66            // halo-padded width/height
#define PPIX (HP*HP)     // 4356 padded pixels per sample
#define KTOT 2304        // 9 * 256
#define NKT 36           // K-tiles of 64

__device__ __forceinline__ u16 f2bf(float f){
    union { float f; unsigned int u; } v; v.f = f;
    return (u16)((v.u + 0x7FFFu + ((v.u >> 16) & 1u)) >> 16);
}

__device__ __forceinline__ void gload(const u16* g, u16* l){
    __builtin_amdgcn_global_load_lds(
        (const __attribute__((address_space(1))) unsigned int*)g,
        (__attribute__((address_space(3))) unsigned int*)l, 16, 0, 0);
}

// -------- 0) zero halo borders of xt2 + zero pooled --------
__global__ void k_zero(u16* __restrict__ xt2, float* __restrict__ pooled){
    int gid = blockIdx.x*256 + threadIdx.x;
    if (gid < B_*CIN) pooled[gid] = 0.f;
    int u4 = gid & 31;
    int pl = gid >> 5;
    if (pl >= B_*260) return;
    int b = pl / 260;
    int pi = pl - b*260;
    int y, x;
    if (pi < 66)      { y = 0;  x = pi; }
    else if (pi < 132){ y = 65; x = pi - 66; }
    else { int q = pi - 132; y = 1 + (q >> 1); x = (q & 1) ? 65 : 0; }
    uint4 z = {0u,0u,0u,0u};
    *(uint4*)(xt2 + ((size_t)b*PPIX + y*HP + x)*CIN + u4*8) = z;
}

// -------- 1) transpose+convert x -> xt2[b][(y+1)*66+(x+1)][cin] bf16, fused pool --------
__global__ void k_xt(const float* __restrict__ x, u16* __restrict__ xt2,
                     float* __restrict__ pooled){
    __shared__ float tile[64][65];
    int bid = blockIdx.x;
    int b = bid >> 8, ct = (bid >> 6) & 3, pt = bid & 63;
    int c0 = ct*64, p0 = pt*64, t = threadIdx.x;
    #pragma unroll
    for (int iter = 0; iter < 4; ++iter){
        int idx = t*4 + iter*1024;
        int r = idx >> 6, c4 = idx & 63;
        float4 v = *(const float4*)(x + ((size_t)(b*CIN + c0 + r))*NPIX + p0 + c4);
        tile[r][c4+0] = v.x; tile[r][c4+1] = v.y; tile[r][c4+2] = v.z; tile[r][c4+3] = v.w;
        float rs = v.x + v.y + v.z + v.w;
        #pragma unroll
        for (int off = 1; off < 16; off <<= 1) rs += __shfl_xor(rs, off, 64);
        if ((t & 15) == 0) atomicAdd(&pooled[b*CIN + c0 + r], rs);
    }
    __syncthreads();
    #pragma unroll
    for (int iter = 0; iter < 4; ++iter){
        int idx = t*4 + iter*1024;
        int pr = idx >> 6, cc = idx & 63;
        ushort4 u;
        u.x = f2bf(tile[cc+0][pr]);
        u.y = f2bf(tile[cc+1][pr]);
        u.z = f2bf(tile[cc+2][pr]);
        u.w = f2bf(tile[cc+3][pr]);
        int p = p0 + pr;
        int yy = p >> 6, xx = p & 63;
        *(ushort4*)(xt2 + ((size_t)b*PPIX + (yy+1)*HP + (xx+1))*CIN + c0 + cc) = u;
    }
}

// -------- 2) routing + aggregated bias --------
__global__ void k_route(const float* __restrict__ pooled, const float* __restrict__ rw,
                        const float* __restrict__ rb, const float* __restrict__ bias,
                        float* __restrict__ routing, float* __restrict__ aggb)
{
    __shared__ float r_s[B_*E_];
    int t = threadIdx.x;
    if (t < B_*E_){
        int b = t >> 3, e = t & 7;
        float s = 0.f;
        const float* pp = pooled + b*CIN;
        const float* wp = rw + e*CIN;
        for (int i = 0; i < CIN; ++i) s += pp[i]*wp[i];
        s = s * (1.0f/(float)NPIX) + rb[e];
        float r = 1.0f/(1.0f + __expf(-s));
        routing[t] = r;
        r_s[t] = r;
    }
    __syncthreads();
    for (int idx = t; idx < B_*COUT; idx += 256){
        int b = idx >> 8, o = idx & 255;
        float s = 0.f;
        #pragma unroll
        for (int e = 0; e < E_; ++e) s += r_s[b*E_+e]*bias[e*COUT+o];
        aggb[idx] = s;
    }
}

// -------- 3) aggregated weights, LDS-coalesced read, layout [b][o][tap][cin] --------
__global__ void k_aggw(const float* __restrict__ weight, const float* __restrict__ routing,
                       u16* __restrict__ aggw)
{
    __shared__ float wls[E_][2304];
    __shared__ float r_s[B_*E_];
    int o = blockIdx.x, t = threadIdx.x;
    if (t < B_*E_) r_s[t] = routing[t];
    #pragma unroll
    for (int e = 0; e < E_; ++e){
        const float4* src = (const float4*)(weight + ((size_t)(e*COUT + o))*2304);
        float4* dst = (float4*)wls[e];
        #pragma unroll
        for (int i = 0; i < 3; ++i){
            int idx = t + i*256;
            if (idx < 576) dst[idx] = src[idx];
        }
    }
    __syncthreads();
    float w[E_][9];
    #pragma unroll
    for (int e = 0; e < E_; ++e)
        #pragma unroll
        for (int tp = 0; tp < 9; ++tp) w[e][tp] = wls[e][t*9 + tp];
    for (int b = 0; b < B_; ++b){
        float acc[9];
        #pragma unroll
        for (int tp = 0; tp < 9; ++tp) acc[tp] = 0.f;
        #pragma unroll
        for (int e = 0; e < E_; ++e){
            float r = r_s[b*E_+e];
            #pragma unroll
            for (int tp = 0; tp < 9; ++tp) acc[tp] += r*w[e][tp];
        }
        #pragma unroll
        for (int tp = 0; tp < 9; ++tp)
            aggw[(((size_t)(b*COUT + o))*9 + tp)*CIN + t] = f2bf(acc[tp]);
    }
}

// -------- 4) 256x256-tile conv: full-tile frag residency, read-early/compute-late --------
__global__ __launch_bounds__(512, 2) void k_conv(
    const u16* __restrict__ aggw, const u16* __restrict__ xt2,
    const float* __restrict__ aggb, float* __restrict__ out)
{
    __shared__ __align__(16) u16 lds[65536];   // 2 buf x (A 256x64 + B 256x64) bf16

    int orig = blockIdx.x;
    int bid = (orig & 7)*32 + (orig >> 3);     // bijective XCD swizzle

    int b  = bid >> 4;
    int nt = bid & 15;
    int y0 = nt << 2;

    int t = threadIdx.x;
    int lane = t & 63;
    int w = t >> 6;
    int wm = (w >> 2) << 7;
    int wn = (w & 3) << 6;
    int l16 = lane & 15;
    int kh4 = lane >> 4;
    int sw  = l16 & 7;

    int tr = t >> 3;
    int tc = t & 7;
    int sc = tc ^ (tr & 7);

    const u16* aSrc = aggw + (size_t)b*COUT*9*CIN + (size_t)tr*KTOT + sc*8;
    const u16* bSrc = xt2 + ((size_t)b*PPIX + (size_t)y0*HP + tr)*CIN + sc*8;

    f32x4 acc[8][4];
    #pragma unroll
    for (int i = 0; i < 8; ++i)
        #pragma unroll
        for (int j = 0; j < 4; ++j){
            f32x4 z = {0.f,0.f,0.f,0.f};
            acc[i][j] = z;
        }

    auto stage = [&](int kt, int bufn){
        int tap = kt >> 2;
        int c0  = (kt & 3) << 6;
        int kh  = tap / 3, kw = tap - kh*3;
        const u16* a0 = aSrc + tap*CIN + c0;
        const u16* b0 = bSrc + (kh*HP + kw)*CIN + c0;
        u16* dA = lds + bufn*32768 + w*512;
        u16* dB = dA + 16384;
        #pragma unroll
        for (int i = 0; i < 4; ++i)
            gload(a0 + (size_t)i*64*KTOT, dA + i*4096);
        #pragma unroll
        for (int i = 0; i < 4; ++i)
            gload(b0 + (size_t)i*HP*CIN, dB + i*4096);
    };

    int ck0 = ((kh4    ) ^ sw) * 8;
    int ck1 = ((kh4 | 4) ^ sw) * 8;

    stage(0, 0);
    __syncthreads();

    int buf = 0;
    #pragma unroll 2
    for (int kt = 0; kt < NKT; ++kt){
        const u16* LA = lds + buf*32768;
        const u16* LB = LA + 16384;

        bf16x8 af[2][4][2];    // [qm][mf][khalf]
        bf16x8 bfr[2][2][2];   // [qn][nf][khalf]

        // critical path: first-quadrant fragments
        #pragma unroll
        for (int mf = 0; mf < 4; ++mf){
            int ro = (wm + mf*16 + l16) * 64;
            af[0][mf][0] = *(const bf16x8*)(LA + ro + ck0);
            af[0][mf][1] = *(const bf16x8*)(LA + ro + ck1);
        }
        #pragma unroll
        for (int nf = 0; nf < 2; ++nf){
            int ro = (wn + nf*16 + l16) * 64;
            bfr[0][nf][0] = *(const bf16x8*)(LB + ro + ck0);
            bfr[0][nf][1] = *(const bf16x8*)(LB + ro + ck1);
        }

        // prefetch next K-tile into other buffer (lands by the tile-end drain)
        if (kt < NKT-1) stage(kt+1, buf^1);

        // remaining fragments
        #pragma unroll
        for (int nf = 0; nf < 2; ++nf){
            int ro = (wn + 32 + nf*16 + l16) * 64;
            bfr[1][nf][0] = *(const bf16x8*)(LB + ro + ck0);
            bfr[1][nf][1] = *(const bf16x8*)(LB + ro + ck1);
        }
        #pragma unroll
        for (int mf = 0; mf < 4; ++mf){
            int ro = (wm + 64 + mf*16 + l16) * 64;
            af[1][mf][0] = *(const bf16x8*)(LA + ro + ck0);
            af[1][mf][1] = *(const bf16x8*)(LA + ro + ck1);
        }

        // 4 quadrant MFMA clusters (compiler overlaps with the read stream)
        #pragma unroll
        for (int qm = 0; qm < 2; ++qm)
            #pragma unroll
            for (int qn = 0; qn < 2; ++qn){
                __builtin_amdgcn_s_setprio(1);
                #pragma unroll
                for (int mf = 0; mf < 4; ++mf)
                    #pragma unroll
                    for (int nf = 0; nf < 2; ++nf){
                        acc[qm*4+mf][qn*2+nf] = __builtin_amdgcn_mfma_f32_16x16x32_bf16(
                            af[qm][mf][0], bfr[qn][nf][0], acc[qm*4+mf][qn*2+nf], 0, 0, 0);
                        acc[qm*4+mf][qn*2+nf] = __builtin_amdgcn_mfma_f32_16x16x32_bf16(
                            af[qm][mf][1], bfr[qn][nf][1], acc[qm*4+mf][qn*2+nf], 0, 0, 0);
                    }
                __builtin_amdgcn_s_setprio(0);
            }

        __syncthreads();   // vmcnt(0)+lgkmcnt(0)+barrier: next buffer staged, reads done
        buf ^= 1;
    }

    const float* ab = aggb + b*COUT;
    float* outp = out + ((size_t)b*COUT)*NPIX + nt*256;
    #pragma unroll
    for (int mf8 = 0; mf8 < 8; ++mf8){
        #pragma unroll
        for (int v = 0; v < 4; ++v){
            int r = wm + mf8*16 + kh4*4 + v;
            float bias_r = ab[r];
            float* orow = outp + (size_t)r*NPIX;
            #pragma unroll
            for (int nf = 0; nf < 4; ++nf)
                orow[wn + nf*16 + l16] = acc[mf8][nf][v] + bias_r;
        }
    }
}

extern "C" void kernel_launch(void* const* d_in, const int* in_sizes, int n_in,
                              void* d_out, int out_size, void* d_ws, size_t ws_size,
                              hipStream_t stream)
{
    const float* x      = (const float*)d_in[0];
    const float* weight = (const float*)d_in[1];
    const float* bias   = (const float*)d_in[2];
    const float* rw     = (const float*)d_in[3];
    const float* rb     = (const float*)d_in[4];
    float* out = (float*)d_out;

    char* ws = (char*)d_ws;
    u16*   aggw    = (u16*)(ws);                          // 18,874,368 B
    u16*   xt2     = (u16*)(ws + 18874368);               // 35,684,352 B (halo 66x66)
    float* pooled  = (float*)(ws + 54558720);             // 16 KB
    float* routing = (float*)(ws + 54558720 + 16384);     // 512 B
    float* aggb    = (float*)(ws + 54558720 + 16384 + 512); // 16 KB

    k_zero <<<520,  256, 0, stream>>>(xt2, pooled);
    k_xt   <<<4096, 256, 0, stream>>>(x, xt2, pooled);
    k_route<<<1,    256, 0, stream>>>(pooled, rw, rb, bias, routing, aggb);
    k_aggw <<<COUT, 256, 0, stream>>>(weight, routing, aggw);
    k_conv <<<256,  512, 0, stream>>>(aggw, xt2, aggb, out);
}